// Round 4
// baseline (599.271 us; speedup 1.0000x reference)
//
#include <hip/hip_runtime.h>

#define IN_CH 128
#define OUT_CH 128
#define LDSPAD 136   // padded row stride (elements); 16B-aligned fragment reads

typedef short bf16x8 __attribute__((ext_vector_type(8)));
typedef float f32x4  __attribute__((ext_vector_type(4)));

__device__ __forceinline__ unsigned short f32_to_bf16_bits(float f) {
    unsigned u = __builtin_bit_cast(unsigned, f);
    u += 0x7FFFu + ((u >> 16) & 1u);   // RNE; finite values only in this pipeline
    return (unsigned short)(u >> 16);
}
__device__ __forceinline__ float bf16_bits_to_f32(unsigned short b) {
    return __builtin_bit_cast(float, (unsigned)b << 16);
}

// ---------------------------------------------------------------------------
// Kernel 0: runtime dtype detection (1 block). flags[0]=X fp32, flags[1]=W1 fp32,
// flags[2]=W2 fp32, flags[3]=idx int64
// ---------------------------------------------------------------------------
__global__ void detect_kernel(const unsigned short* __restrict__ X,
                              const unsigned short* __restrict__ W1,
                              const unsigned short* __restrict__ W2,
                              const int* __restrict__ idx,
                              int* __restrict__ flags) {
    __shared__ int red[4];
    const int t = threadIdx.x;
    if (t < 4) red[t] = 0;
    __syncthreads();
    #pragma unroll
    for (int w = 0; w < 3; ++w) {
        const unsigned short* p = (w == 0) ? X : (w == 1) ? W1 : W2;
        int crazy = 0;
        for (int j = t; j < 512; j += 256) {
            const unsigned short h = p[j];
            const int e = (h >> 7) & 0xFF;
            const int man = h & 0x7F;
            if (e >= 0x90 || (e == 0 && man != 0)) crazy++;
        }
        if (crazy) atomicAdd(&red[w], crazy);
    }
    {   // idx: odd int32 words are int64 high-words (all 0 since values < 10000)
        if (idx[2 * t + 1] != 0) atomicAdd(&red[3], 1);
    }
    __syncthreads();
    if (t == 0) {
        flags[0] = red[0] > 16 ? 1 : 0;
        flags[1] = red[1] > 16 ? 1 : 0;
        flags[2] = red[2] > 16 ? 1 : 0;
        flags[3] = red[3] < 8  ? 1 : 0;
    }
}

// ---------------------------------------------------------------------------
// Kernel 1: per-segment counts (idx-width adaptive)
// ---------------------------------------------------------------------------
__global__ void count_kernel(const int* __restrict__ idx, int* __restrict__ cnt,
                             const int* __restrict__ flags, int n) {
    const int sh = flags[3];
    int i = blockIdx.x * blockDim.x + threadIdx.x;
    if (i < n) atomicAdd(&cnt[idx[(size_t)i << sh]], 1);
}

// ---------------------------------------------------------------------------
// Kernel 2: exclusive scan of counts -> off[] and cur[]
// ---------------------------------------------------------------------------
__global__ void scan_kernel(const int* __restrict__ cnt, int* __restrict__ off,
                            int* __restrict__ cur, int dim) {
    __shared__ int wtot[16];
    __shared__ int woff[16];
    __shared__ int carry_s;
    const int tid = threadIdx.x;
    const int wv = tid >> 6, ln = tid & 63;
    if (tid == 0) carry_s = 0;
    __syncthreads();
    for (int base = 0; base < dim; base += 1024) {
        const int i = base + tid;
        const int orig = (i < dim) ? cnt[i] : 0;
        int v = orig;
        #pragma unroll
        for (int d = 1; d < 64; d <<= 1) {
            int w = __shfl_up(v, d, 64);
            if (ln >= d) v += w;
        }
        if (ln == 63) wtot[wv] = v;
        __syncthreads();
        if (tid == 0) {
            int acc = carry_s;
            #pragma unroll
            for (int k = 0; k < 16; ++k) { woff[k] = acc; acc += wtot[k]; }
            carry_s = acc;
        }
        __syncthreads();
        const int excl = woff[wv] + v - orig;
        if (i < dim) { off[i] = excl; cur[i] = excl; }
        __syncthreads();
    }
}

// ---------------------------------------------------------------------------
// Kernel 3: build row permutation grouped by segment
// ---------------------------------------------------------------------------
__global__ void perm_kernel(const int* __restrict__ idx, int* __restrict__ cur,
                            int* __restrict__ perm, const int* __restrict__ flags,
                            int n) {
    const int sh = flags[3];
    int i = blockIdx.x * blockDim.x + threadIdx.x;
    if (i < n) {
        const int s = idx[(size_t)i << sh];
        const int p = atomicAdd(&cur[s], 1);
        perm[p] = i;
    }
}

// ---------------------------------------------------------------------------
// Kernel 4 (v3b): fused MLP + per-segment row reduction, FLAT CHUNK STREAM.
// Each block builds an LDS table of its <=16 segments (start,cnt,cum-chunks),
// then iterates one continuous stream of 32-row chunks with a 2-deep A/B
// gather pipeline: at chunk j we ds_write the buffer (loaded at j-2), re-issue
// it for chunk j+2 using a perm value prefetched at j-2, so the perm->X chain
// (~1200cy) hides under ~2 chunk-periods of MFMA work. Segment completion is
// just shuffle-reduce + store + sum=0 (no pipeline restart, no atomics).
// Template<XF32> dual-launch keeps the fp32-X convert path out of the hot
// kernel's registers.
// ---------------------------------------------------------------------------
template <int XF32>
__global__ __launch_bounds__(512, 4)
void mlp_gather_kernel(const unsigned short* __restrict__ X,
                       const int* __restrict__ perm,
                       const int* __restrict__ off,
                       const int* __restrict__ cnt,
                       const unsigned short* __restrict__ W1,
                       const unsigned short* __restrict__ B1,
                       const unsigned short* __restrict__ W2,
                       const unsigned short* __restrict__ B2,
                       float* __restrict__ out,
                       const int* __restrict__ flags,
                       int dim)
{
    if (flags[0] != XF32) return;

    __shared__ short lds_x[32 * LDSPAD];
    __shared__ short lds_h[32 * LDSPAD];
    __shared__ int s_sid[16], s_cnt[16], s_start[16], s_cum[17];

    const int w1f32 = flags[1];
    const int w2f32 = flags[2];

    const int tid  = threadIdx.x;
    const int wave = tid >> 6;    // 0..7
    const int lane = tid & 63;
    const int m    = lane & 15;   // A row / B col / D col
    const int quad = lane >> 4;
    const int n    = wave * 16 + m;   // this lane's output channel

    // Preload W1/W2 B-fragments (B[k][n]=W[n][k] -> 8 contiguous k from row n
    // of row-major W) and biases.
    bf16x8 w1f[4], w2f[4];
    float  b1c, b2c;
    b1c = w1f32 ? ((const float*)B1)[n] : bf16_bits_to_f32(B1[n]);
    b2c = w2f32 ? ((const float*)B2)[n] : bf16_bits_to_f32(B2[n]);
    #pragma unroll
    for (int kc = 0; kc < 4; ++kc) {
        const int ko = kc * 32 + quad * 8;
        if (w1f32) {
            const float* Wf = (const float*)W1;
            f32x4 lo = *(const f32x4*)(Wf + n * IN_CH + ko);
            f32x4 hi = *(const f32x4*)(Wf + n * IN_CH + ko + 4);
            bf16x8 v;
            #pragma unroll
            for (int j = 0; j < 4; ++j) {
                v[j]     = (short)f32_to_bf16_bits(lo[j]);
                v[4 + j] = (short)f32_to_bf16_bits(hi[j]);
            }
            w1f[kc] = v;
        } else {
            w1f[kc] = *(const bf16x8*)(W1 + n * IN_CH + ko);
        }
        if (w2f32) {
            const float* Wf = (const float*)W2;
            f32x4 lo = *(const f32x4*)(Wf + n * OUT_CH + ko);
            f32x4 hi = *(const f32x4*)(Wf + n * OUT_CH + ko + 4);
            bf16x8 v;
            #pragma unroll
            for (int j = 0; j < 4; ++j) {
                v[j]     = (short)f32_to_bf16_bits(lo[j]);
                v[4 + j] = (short)f32_to_bf16_bits(hi[j]);
            }
            w2f[kc] = v;
        } else {
            w2f[kc] = *(const bf16x8*)(W2 + n * OUT_CH + ko);
        }
    }

    const int srow = tid >> 4;   // 0..31: staged row within chunk
    const int sseg = tid & 15;   // 8-element segment within the row

    const int G   = gridDim.x;
    const int bid = blockIdx.x;
    const int A   = (bid < dim) ? (dim - 1 - bid) / G + 1 : 0;  // segments owned

    for (int w0 = 0; w0 < A; w0 += 16) {
        int nseg = (A - w0) < 16 ? (A - w0) : 16;
        if (nseg <= 0) break;

        __syncthreads();   // protect table rewrite vs previous window's reads
        if (tid < nseg) {
            const int s = bid + (w0 + tid) * G;
            s_sid[tid]   = s;
            s_cnt[tid]   = cnt[s];
            s_start[tid] = off[s];
        }
        __syncthreads();
        if (tid == 0) {
            int acc = 0;
            s_cum[0] = 0;
            for (int i = 0; i < nseg; ++i) {
                acc += (s_cnt[i] + 31) >> 5;
                s_cum[i + 1] = acc;
            }
        }
        __syncthreads();
        const int C = s_cum[nseg];   // total chunks this window

        // row index (original X row) staged by this thread for chunk jq; -1 = pad
        auto rowidx = [&](int jq, int khint) -> int {
            if (jq >= C) return -1;
            int kk = khint;
            while (kk + 1 < nseg && jq >= s_cum[kk + 1]) ++kk;
            const int gr = (jq - s_cum[kk]) * 32 + srow;
            return (gr < s_cnt[kk]) ? perm[s_start[kk] + gr] : -1;
        };
        // gather one row-fragment (8 bf16); zero for pad rows
        auto xload = [&](int pr) -> bf16x8 {
            bf16x8 v = {0, 0, 0, 0, 0, 0, 0, 0};
            if (pr >= 0) {
                if (XF32) {
                    const float* Xf = (const float*)X;
                    f32x4 lo = *(const f32x4*)(Xf + (size_t)pr * IN_CH + sseg * 8);
                    f32x4 hi = *(const f32x4*)(Xf + (size_t)pr * IN_CH + sseg * 8 + 4);
                    #pragma unroll
                    for (int j = 0; j < 4; ++j) {
                        v[j]     = (short)f32_to_bf16_bits(lo[j]);
                        v[4 + j] = (short)f32_to_bf16_bits(hi[j]);
                    }
                } else {
                    v = *(const bf16x8*)(X + (size_t)pr * IN_CH + sseg * 8);
                }
            }
            return v;
        };

        int   k   = 0;
        float sum = 0.f;

        auto body = [&](int j, bf16x8& xb, int& pr) {
            while (j >= s_cum[k + 1]) ++k;          // uniform; handles empty segs
            const int c    = s_cnt[k];
            const int base = (j - s_cum[k]) * 32;

            // commit staged chunk j; immediately re-issue buffer for chunk j+2
            *(bf16x8*)&lds_x[srow * LDSPAD + sseg * 8] = xb;
            xb = xload(pr);            // consumed 2 chunk-periods from now
            pr = rowidx(j + 4, k);     // perm value for the NEXT refill of xb
            __syncthreads();

            // ---- layer 1: two 16-row sub-tiles x this wave's 16 channels ----
            f32x4 acc0 = {0.f, 0.f, 0.f, 0.f}, acc1 = {0.f, 0.f, 0.f, 0.f};
            #pragma unroll
            for (int kc = 0; kc < 4; ++kc) {
                const int ko = kc * 32 + quad * 8;
                bf16x8 a0 = *(const bf16x8*)&lds_x[m * LDSPAD + ko];
                bf16x8 a1 = *(const bf16x8*)&lds_x[(16 + m) * LDSPAD + ko];
                acc0 = __builtin_amdgcn_mfma_f32_16x16x32_bf16(a0, w1f[kc], acc0, 0, 0, 0);
                acc1 = __builtin_amdgcn_mfma_f32_16x16x32_bf16(a1, w1f[kc], acc1, 0, 0, 0);
            }
            #pragma unroll
            for (int r = 0; r < 4; ++r) {
                float v0 = acc0[r] + b1c;
                v0 = v0 > 0.f ? v0 : 0.f;
                lds_h[(quad * 4 + r) * LDSPAD + n] = (short)f32_to_bf16_bits(v0);
                float v1 = acc1[r] + b1c;
                v1 = v1 > 0.f ? v1 : 0.f;
                lds_h[(16 + quad * 4 + r) * LDSPAD + n] = (short)f32_to_bf16_bits(v1);
            }
            __syncthreads();

            // ---- layer 2 ----
            f32x4 acc2_0 = {0.f, 0.f, 0.f, 0.f}, acc2_1 = {0.f, 0.f, 0.f, 0.f};
            #pragma unroll
            for (int kc = 0; kc < 4; ++kc) {
                const int ko = kc * 32 + quad * 8;
                bf16x8 a0 = *(const bf16x8*)&lds_h[m * LDSPAD + ko];
                bf16x8 a1 = *(const bf16x8*)&lds_h[(16 + m) * LDSPAD + ko];
                acc2_0 = __builtin_amdgcn_mfma_f32_16x16x32_bf16(a0, w2f[kc], acc2_0, 0, 0, 0);
                acc2_1 = __builtin_amdgcn_mfma_f32_16x16x32_bf16(a1, w2f[kc], acc2_1, 0, 0, 0);
            }

            // ---- relu+bias per row, masked in-lane row reduction ----
            #pragma unroll
            for (int r = 0; r < 4; ++r) {
                if (base + quad * 4 + r < c) {
                    float v = acc2_0[r] + b2c;
                    sum += (v > 0.f ? v : 0.f);
                }
                if (base + 16 + quad * 4 + r < c) {
                    float v = acc2_1[r] + b2c;
                    sum += (v > 0.f ? v : 0.f);
                }
            }

            // ---- segment complete: cross-quad reduce + single store ----
            if (j + 1 == s_cum[k + 1]) {
                float t = sum;
                t += __shfl_xor(t, 16, 64);
                t += __shfl_xor(t, 32, 64);
                if (quad == 0) {
                    const int cd = c > 1 ? c : 1;
                    out[(size_t)s_sid[k] * OUT_CH + n] = t / (float)cd;
                }
                sum = 0.f;
            }
        };

        if (C > 0) {
            // ---- 2-deep A/B pipeline prologue ----
            int prA = rowidx(0, 0);
            int prB = rowidx(1, 0);
            bf16x8 xA = xload(prA);
            bf16x8 xB = xload(prB);
            prA = rowidx(2, 0);
            prB = rowidx(3, 0);

            for (int j = 0; j < C; j += 2) {
                body(j, xA, prA);
                if (j + 1 < C) body(j + 1, xB, prB);
            }
        }

        // empty segments (c==0) never produce chunks: write zeros
        for (int k2 = 0; k2 < nseg; ++k2) {
            if (s_cnt[k2] == 0 && quad == 0)
                out[(size_t)s_sid[k2] * OUT_CH + n] = 0.f;
        }
    }
}

extern "C" void kernel_launch(void* const* d_in, const int* in_sizes, int n_in,
                              void* d_out, int out_size, void* d_ws, size_t ws_size,
                              hipStream_t stream) {
    // size-based input resolution
    int iX = 0;
    for (int i = 1; i < n_in; ++i)
        if (in_sizes[i] > in_sizes[iX]) iX = i;
    const int n_src = in_sizes[iX] / IN_CH;
    int iI = -1, iW1 = -1, iW2 = -1, iB1 = -1, iB2 = -1;
    for (int i = 0; i < n_in; ++i) {
        if (i == iX) continue;
        const int s = in_sizes[i];
        if (s == n_src && iI < 0) iI = i;
        else if (s == IN_CH * OUT_CH) { if (iW1 < 0) iW1 = i; else if (iW2 < 0) iW2 = i; }
        else if (s == OUT_CH) { if (iB1 < 0) iB1 = i; else if (iB2 < 0) iB2 = i; }
    }

    const unsigned short* X  = (const unsigned short*)d_in[iX];
    const int*            ix = (const int*)d_in[iI];
    const unsigned short* W1 = (const unsigned short*)d_in[iW1];
    const unsigned short* B1 = (const unsigned short*)d_in[iB1];
    const unsigned short* W2 = (const unsigned short*)d_in[iW2];
    const unsigned short* B2 = (const unsigned short*)d_in[iB2];
    float* out = (float*)d_out;

    const int dim = out_size / OUT_CH;

    int* flags = (int*)d_ws;                       // [0,256) reserved
    int* cnt   = (int*)((char*)d_ws + 256);        // dim
    int* off   = cnt + dim;                        // dim
    int* cur   = off + dim;                        // dim
    int* perm  = cur + dim;                        // n_src

    hipMemsetAsync(cnt, 0, (size_t)dim * sizeof(int), stream);

    detect_kernel<<<1, 256, 0, stream>>>(X, W1, W2, ix, flags);

    count_kernel<<<(n_src + 255) / 256, 256, 0, stream>>>(ix, cnt, flags, n_src);

    scan_kernel<<<1, 1024, 0, stream>>>(cnt, off, cur, dim);

    perm_kernel<<<(n_src + 255) / 256, 256, 0, stream>>>(ix, cur, perm, flags, n_src);

    int grid = dim < 2048 ? dim : 2048;
    if (grid < 1) grid = 1;
    mlp_gather_kernel<0><<<grid, 512, 0, stream>>>(X, perm, off, cnt, W1, B1, W2, B2,
                                                   out, flags, dim);
    mlp_gather_kernel<1><<<grid, 512, 0, stream>>>(X, perm, off, cnt, W1, B1, W2, B2,
                                                   out, flags, dim);
}